// Round 1
// baseline (136.757 us; speedup 1.0000x reference)
//
#include <hip/hip_runtime.h>

// Problem constants (from reference): T=64, B=512, H=512, SEQ=384.
#define T_DIM 64
#define B_DIM 512
#define H_DIM 512
#define H4    (H_DIM / 4)   // 128 float4 per row

// Kernel 1: per batch element, replay the op sequence and record, for each
// step t, which input row (time index) the output reads — or -1 for
// initial_hidden. Stack slot p>=1 holds inputs[writers[p]]; slot 0 is never
// written (writes go to pos+1 >= 1) so pos==0 => initial_hidden, handled by
// initializing writers[] to -1.
__global__ void compute_src_kernel(const int* __restrict__ ops,
                                   int* __restrict__ src) {
    int b = blockIdx.x * blockDim.x + threadIdx.x;
    if (b >= B_DIM) return;
    int writers[T_DIM + 2];
#pragma unroll
    for (int i = 0; i < T_DIM + 2; ++i) writers[i] = -1;
    int pos = 0;
    for (int t = 0; t < T_DIM; ++t) {
        writers[pos + 1] = t;          // write x_t at slot pos+1
        pos += ops[t * B_DIM + b];     // pos update (guaranteed >= 0)
        src[t * B_DIM + b] = writers[pos];  // read at updated pos
    }
}

// Kernel 2: vectorized gather. out[row, h] = (src[row] < 0)
//   ? initial_hidden[h] : inputs[src[row]*B + b, h],  row = t*B + b.
__global__ __launch_bounds__(256) void gather_kernel(
        const float4* __restrict__ in, const float4* __restrict__ init,
        const int* __restrict__ src, float4* __restrict__ out) {
    int idx = blockIdx.x * blockDim.x + threadIdx.x;  // float4 index
    int row = idx >> 7;       // / H4
    int h4  = idx & (H4 - 1);
    int s   = src[row];       // broadcast across the 128 lanes of a row
    int b   = row & (B_DIM - 1);
    const float4* p = (s < 0)
        ? (init + h4)
        : (in + ((size_t)(s * B_DIM + b)) * H4 + h4);
    out[idx] = *p;
}

extern "C" void kernel_launch(void* const* d_in, const int* in_sizes, int n_in,
                              void* d_out, int out_size, void* d_ws, size_t ws_size,
                              hipStream_t stream) {
    const float* inputs = (const float*)d_in[0];   // (T,B,H) fp32
    const float* init   = (const float*)d_in[1];   // (H,) fp32
    const int*   ops    = (const int*)d_in[2];     // (T,B) int32
    // d_in[3] = seq_len (only sizes the stack; unused here)

    int* src = (int*)d_ws;  // T*B int32 = 128 KiB scratch

    compute_src_kernel<<<(B_DIM + 255) / 256, 256, 0, stream>>>(ops, src);

    const int total4 = T_DIM * B_DIM * H4;  // 4,194,304
    gather_kernel<<<total4 / 256, 256, 0, stream>>>(
        (const float4*)inputs, (const float4*)init, src, (float4*)d_out);
}

// Round 3
// 120.668 us; speedup vs baseline: 1.1333x; 1.1333x over previous
//
#include <hip/hip_runtime.h>

// Problem constants (from reference): T=64, B=512, H=512, SEQ=384.
#define T_DIM 64
#define B_DIM 512
#define H_DIM 512
#define H4    (H_DIM / 4)   // 128 float4 per row

// Native clang vector type: __builtin_nontemporal_store rejects HIP's
// HIP_vector_type<float,4> struct but accepts ext_vector_type. Same 16B
// layout and dwordx4 codegen.
typedef float vfloat4 __attribute__((ext_vector_type(4)));

// Fused kernel. Grid: 2048 blocks = B * 4 quarters of T. Block: 256 = 4 waves.
//
// Phase 1 (per wave, no barriers): lane t computes src[t] for this block's b:
//   pos_t  = inclusive prefix sum of ops[:,b]        (6 __shfl_up steps)
//   w_t    = pos_t - op_t + 1                        (slot written at step t)
//   src_t  = last t' <= t with w_{t'} == pos_t, else -1 (-1 => initial_hidden)
// computed via a per-wave LDS table masks[65]: bit t' set in masks[w_{t'}],
// then src_t = MSB of (masks[pos_t] & bits[0..t]). Slot 0 is never written
// (w >= 1) so pos_t == 0 naturally yields -1. pos_t <= t+1 <= 64, w <= 64.
//
// Phase 2: wave handles 4 rows t; s broadcast via __shfl; copy 2 KiB row
// (128 float4) as 2 coalesced float4 per lane. Nontemporal stores (out is
// never re-read) keep L2 for gather re-reads of input rows.
__global__ __launch_bounds__(256) void state_stack_fused(
        const vfloat4* __restrict__ in,    // (T*B, H4)
        const vfloat4* __restrict__ init,  // (H4,)
        const int*     __restrict__ ops,   // (T, B)
        vfloat4*       __restrict__ out) { // (T*B, H4)
    const int b    = blockIdx.x >> 2;
    const int tq   = blockIdx.x & 3;      // which 16-row quarter of T
    const int wave = threadIdx.x >> 6;
    const int lane = threadIdx.x & 63;

    // ---- Phase 1: wave-parallel src computation (lane == step t) ----
    const int op = ops[lane * B_DIM + b];
    int pos = op;
#pragma unroll
    for (int d = 1; d < 64; d <<= 1) {
        int n = __shfl_up(pos, d, 64);
        if (lane >= d) pos += n;
    }
    const int w = pos - op + 1;           // write slot at this step, in [1,64]

    __shared__ unsigned long long masks[4][65];
    masks[wave][lane] = 0ull;
    if (lane == 0) masks[wave][64] = 0ull;
    __builtin_amdgcn_wave_barrier();      // keep LDS ops in program order
    atomicOr(&masks[wave][w], 1ull << lane);
    __builtin_amdgcn_wave_barrier();
    unsigned long long m = masks[wave][pos];
    m &= (lane == 63) ? ~0ull : ((1ull << (lane + 1)) - 1ull);
    const int my_src = m ? (63 - __builtin_clzll(m)) : -1;

    // ---- Phase 2: gather 4 rows of 2 KiB each ----
    const int t0 = tq * 16 + wave * 4;
#pragma unroll
    for (int r = 0; r < 4; ++r) {
        const int t = t0 + r;
        const int s = __shfl(my_src, t, 64);   // broadcast lane t's src
        const vfloat4* src_row = (s < 0)
            ? init
            : in + ((size_t)(s * B_DIM + b)) * H4;
        const vfloat4 v0 = src_row[lane];
        const vfloat4 v1 = src_row[lane + 64];
        vfloat4* dst = out + ((size_t)(t * B_DIM + b)) * H4;
        __builtin_nontemporal_store(v0, dst + lane);
        __builtin_nontemporal_store(v1, dst + lane + 64);
    }
}

extern "C" void kernel_launch(void* const* d_in, const int* in_sizes, int n_in,
                              void* d_out, int out_size, void* d_ws, size_t ws_size,
                              hipStream_t stream) {
    const float* inputs = (const float*)d_in[0];   // (T,B,H) fp32
    const float* init   = (const float*)d_in[1];   // (H,) fp32
    const int*   ops    = (const int*)d_in[2];     // (T,B) int32
    // d_in[3] = seq_len (only sizes the reference's stack; unused here)

    state_stack_fused<<<B_DIM * 4, 256, 0, stream>>>(
        (const vfloat4*)inputs, (const vfloat4*)init, ops, (vfloat4*)d_out);
}